// Round 3
// baseline (519.136 us; speedup 1.0000x reference)
//
#include <hip/hip_runtime.h>

#define N_TOK 16384
#define N_EMB 8192
#define DIM   512
#define KSPLIT 4

typedef __attribute__((ext_vector_type(8))) short bf16x8;
typedef __attribute__((ext_vector_type(16))) float f32x16;
typedef unsigned short u16;

__device__ __forceinline__ u16 f2bf(float f) {
    unsigned u = __float_as_uint(f);
    u += 0x7fffu + ((u >> 16) & 1u);
    return (u16)(u >> 16);
}
__device__ __forceinline__ float bf2f(u16 h) {
    return __uint_as_float(((unsigned)h) << 16);
}

__device__ __forceinline__ void gload16(const void* g, void* l) {
    __builtin_amdgcn_global_load_lds(
        (const __attribute__((address_space(1))) unsigned int*)g,
        (__attribute__((address_space(3))) unsigned int*)l, 16, 0, 0);
}

// ---- prep: interleaved split layout: [row][16 dblocks][hi 32 bf16 | lo 32 bf16] (128 B lines)
__global__ void prep_x_kernel(const float* __restrict__ x, u16* __restrict__ xint) {
    const int tid = threadIdx.x, lane = tid & 63, wvi = tid >> 6;
    const int row = blockIdx.x * 4 + wvi;
    const float* src = x + (size_t)row * DIM + lane * 8;
    float4 v0 = *(const float4*)src;
    float4 v1 = *(const float4*)(src + 4);
    float vv[8] = {v0.x, v0.y, v0.z, v0.w, v1.x, v1.y, v1.z, v1.w};
    bf16x8 hv, lv;
#pragma unroll
    for (int i = 0; i < 8; ++i) {
        u16 h = f2bf(vv[i]);
        hv[i] = (short)h;
        lv[i] = (short)f2bf(vv[i] - bf2f(h));
    }
    u16* dst = xint + (size_t)row * 1024 + (lane >> 2) * 64 + (lane & 3) * 8;
    *(bf16x8*)dst = hv;
    *(bf16x8*)(dst + 32) = lv;
}

__global__ void prep_w_kernel(const float* __restrict__ w, u16* __restrict__ wint,
                              float* __restrict__ wsq) {
    const int tid = threadIdx.x, lane = tid & 63, wvi = tid >> 6;
    const int row = blockIdx.x * 4 + wvi;
    const float* src = w + (size_t)row * DIM + lane * 8;
    float4 v0 = *(const float4*)src;
    float4 v1 = *(const float4*)(src + 4);
    float vv[8] = {v0.x, v0.y, v0.z, v0.w, v1.x, v1.y, v1.z, v1.w};
    bf16x8 hv, lv;
    float s = 0.f;
#pragma unroll
    for (int i = 0; i < 8; ++i) {
        u16 h = f2bf(vv[i]);
        hv[i] = (short)h;
        lv[i] = (short)f2bf(vv[i] - bf2f(h));
        s += vv[i] * vv[i];
    }
    u16* dst = wint + (size_t)row * 1024 + (lane >> 2) * 64 + (lane & 3) * 8;
    *(bf16x8*)dst = hv;
    *(bf16x8*)(dst + 32) = lv;
#pragma unroll
    for (int off = 1; off < 64; off <<= 1) s += __shfl_xor(s, off);
    if (lane == 0) wsq[row] = s;
}

// ---- main: 3-pass split-bf16 GEMM (32x32x16), counted-vmcnt double-buffer, streaming argmin
// LDS per buffer: A [128 rows][128 B line: hi|lo 32 dims] 16 KiB + B same 16 KiB.
// Swizzle (proven shape): granule g (16 B) of row r stored at g' = g ^ (r&7).
#define MFMA3(d, ah, al, bh, bl)                                              \
    d = __builtin_amdgcn_mfma_f32_32x32x16_bf16(ah, bh, d, 0, 0, 0);          \
    d = __builtin_amdgcn_mfma_f32_32x32x16_bf16(ah, bl, d, 0, 0, 0);          \
    d = __builtin_amdgcn_mfma_f32_32x32x16_bf16(al, bh, d, 0, 0, 0);

__global__ __launch_bounds__(256, 2)
void gemm_argmin_kernel(const u16* __restrict__ xint, const u16* __restrict__ wint,
                        const float* __restrict__ wsq,
                        float* __restrict__ wsval, int* __restrict__ wsidx) {
    __shared__ u16 sm[2][2][128 * 64];   // [buf][A/B][128 rows * 64 u16] = 64 KiB
    __shared__ float smq[2][256];        // wsq slices, chunk-parity dbuf (+2 KiB)
    const int tid = threadIdx.x;
    const int lane = tid & 63, wv = tid >> 6;
    const int wm = wv >> 1, wn = wv & 1;

    // XCD-aware decode: 512 blocks; same-csplit blocks land on same XCD pair
    const int bid = blockIdx.x;
    const int xcd = bid & 7;
    const int cs = xcd >> 1;
    const int m = ((xcd & 1) << 6) + (bid >> 3);
    const int RB = m * 128;
    const int CB = cs * 2048;

    const int sg = (lane & 7) ^ (lane >> 3);   // pre-swizzled source granule
    const int srow = lane >> 3;

    float runv[32];
    int   runi[32];
#pragma unroll
    for (int e = 0; e < 32; ++e) { runv[e] = 3.4e38f; runi[e] = 0; }

    const int l7 = lane & 7, l5 = lane >> 5, l31 = lane & 31;
    const int rA0 = wm * 64 + l31;
    const int rB0 = wn * 64 + l31;

    auto stage = [&](int t) {
        const int buf = t & 1;
        const int db = t & 15;
        const int ch1 = (t >> 4) + 1;
        const int cb = CB + (t >> 4) * 128;
        u16* dstA = &sm[buf][0][0];
        u16* dstB = &sm[buf][1][0];
#pragma unroll
        for (int j = 0; j < 4; ++j) {
            int seg = wv * 4 + j;                  // 0..15, wave-uniform
            int r = seg * 8 + srow;
            const u16* srcA = xint + (size_t)(RB + r) * 1024 + db * 64 + sg * 8;
            const u16* srcB = wint + (size_t)(cb + r) * 1024 + db * 64 + sg * 8;
            gload16(srcA, dstA + seg * 512);
            gload16(srcB, dstB + seg * 512);
        }
        // wsq slice for next chunk (redundant across waves/steps; keeps vmcnt uniform)
        gload16(wsq + CB + ((ch1 & 15) << 7) + lane * 4, &smq[ch1 & 1][0]);
    };

    // prologue: wsq slice 0, tiles 0 and 1
    gload16(wsq + CB + lane * 4, &smq[0][0]);
    stage(0);
    stage(1);

    f32x16 a00, a01, a10, a11;
    float wq0 = 0.f, wq1 = 0.f;

    for (int t = 0; t < 256; ++t) {
        if (t < 255) asm volatile("s_waitcnt vmcnt(9)" ::: "memory");
        else         asm volatile("s_waitcnt vmcnt(0)" ::: "memory");
        __builtin_amdgcn_s_barrier();

        if ((t & 15) == 0) {
#pragma unroll
            for (int r = 0; r < 16; ++r) { a00[r] = 0.f; a01[r] = 0.f; a10[r] = 0.f; a11[r] = 0.f; }
        }

        const char* base = (const char*)&sm[t & 1][0][0];
#pragma unroll
        for (int kk = 0; kk < 2; ++kk) {
            const int gh = 2 * kk + l5;            // hi granule (0..3)
            const int offAh = rA0 * 128 + ((gh ^ l7) << 4);
            const int offAl = rA0 * 128 + (((gh + 4) ^ l7) << 4);
            const int offBh = rB0 * 128 + ((gh ^ l7) << 4);
            const int offBl = rB0 * 128 + (((gh + 4) ^ l7) << 4);
            bf16x8 ah0 = *(const bf16x8*)(base + offAh);
            bf16x8 ah1 = *(const bf16x8*)(base + offAh + 4096);   // mi=1: +32 rows
            bf16x8 al0 = *(const bf16x8*)(base + offAl);
            bf16x8 al1 = *(const bf16x8*)(base + offAl + 4096);
            bf16x8 bh0 = *(const bf16x8*)(base + 16384 + offBh);
            bf16x8 bh1 = *(const bf16x8*)(base + 16384 + offBh + 4096);
            bf16x8 bl0 = *(const bf16x8*)(base + 16384 + offBl);
            bf16x8 bl1 = *(const bf16x8*)(base + 16384 + offBl + 4096);
            __builtin_amdgcn_s_setprio(1);
            MFMA3(a00, ah0, al0, bh0, bl0);
            MFMA3(a01, ah0, al0, bh1, bl1);
            MFMA3(a10, ah1, al1, bh0, bl0);
            MFMA3(a11, ah1, al1, bh1, bl1);
            __builtin_amdgcn_s_setprio(0);
        }

        asm volatile("s_waitcnt lgkmcnt(0)" ::: "memory");
        __builtin_amdgcn_sched_barrier(0);
        __builtin_amdgcn_s_barrier();
        if (t < 254) stage(t + 2);

        if ((t & 15) == 0) {
            const int ch = t >> 4;
            wq0 = smq[ch & 1][wn * 64 + l31];
            wq1 = smq[ch & 1][wn * 64 + 32 + l31];
        }
        if ((t & 15) == 15) {
            const int ch = t >> 4;
            const int c0 = CB + ch * 128 + wn * 64 + l31;
#pragma unroll
            for (int mi = 0; mi < 2; ++mi) {
#pragma unroll
                for (int q = 0; q < 16; ++q) {
                    const int e = mi * 16 + q;
                    float s0 = wq0 - 2.0f * (mi ? a10[q] : a00[q]);
                    if (s0 < runv[e]) { runv[e] = s0; runi[e] = c0; }
                    float s1 = wq1 - 2.0f * (mi ? a11[q] : a01[q]);
                    if (s1 < runv[e]) { runv[e] = s1; runi[e] = c0 + 32; }
                }
            }
        }
    }

    // drain everything, then reuse LDS for merge
    asm volatile("s_waitcnt vmcnt(0) lgkmcnt(0)" ::: "memory");
    __builtin_amdgcn_s_barrier();

    float* mv  = (float*)&sm[0][0][0];                 // [2][128]
    int*   mi_ = (int*)((char*)&sm[0][0][0] + 1024);   // [2][128]
#pragma unroll
    for (int mi = 0; mi < 2; ++mi) {
#pragma unroll
        for (int q = 0; q < 16; ++q) {
            float v = runv[mi * 16 + q];
            int   ix = runi[mi * 16 + q];
#pragma unroll
            for (int off = 1; off < 32; off <<= 1) {
                float ov = __shfl_xor(v, off);
                int   oi = __shfl_xor(ix, off);
                if (ov < v || (ov == v && oi < ix)) { v = ov; ix = oi; }
            }
            if (l31 == 0) {
                int rl = wm * 64 + mi * 32 + (q & 3) + 8 * (q >> 2) + 4 * l5;
                mv[wn * 128 + rl]  = v;
                mi_[wn * 128 + rl] = ix;
            }
        }
    }
    __syncthreads();
    if (tid < 128) {
        float v0 = mv[tid];       int i0 = mi_[tid];
        float v1 = mv[128 + tid]; int i1 = mi_[128 + tid];
        if (v1 < v0 || (v1 == v0 && i1 < i0)) { v0 = v1; i0 = i1; }
        wsval[(size_t)(RB + tid) * KSPLIT + cs] = v0;
        wsidx[(size_t)(RB + tid) * KSPLIT + cs] = i0;
    }
}

// ---------------- merge ksplits + gather + loss partials ----------------
__global__ void gather_loss_kernel(const float* __restrict__ w, const float* __restrict__ x,
                                   const float* __restrict__ wsval, const int* __restrict__ wsidx,
                                   float* __restrict__ out, float* __restrict__ lossp) {
    const int tid = threadIdx.x, lane = tid & 63, wvi = tid >> 6;
    const int t = blockIdx.x * 4 + wvi;
    int bi = 0;
    if (lane == 0) {
        float bv = wsval[(size_t)t * KSPLIT];
        bi = wsidx[(size_t)t * KSPLIT];
#pragma unroll
        for (int ks = 1; ks < KSPLIT; ++ks) {
            float v = wsval[(size_t)t * KSPLIT + ks];
            int  ix = wsidx[(size_t)t * KSPLIT + ks];
            if (v < bv || (v == bv && ix < bi)) { bv = v; bi = ix; }
        }
    }
    bi = __shfl(bi, 0);
    const float* wr = w + (size_t)bi * DIM;
    const float* xr = x + (size_t)t * DIM;
    float* orow = out + (size_t)t * DIM;
    float s = 0.f;
#pragma unroll
    for (int j = 0; j < 2; ++j) {
        int d = j * 256 + lane * 4;
        float4 a = *(const float4*)(wr + d);
        float4 b = *(const float4*)(xr + d);
        *(float4*)(orow + d) = a;
        float d0 = a.x - b.x, d1 = a.y - b.y, d2 = a.z - b.z, d3 = a.w - b.w;
        s += d0 * d0 + d1 * d1 + d2 * d2 + d3 * d3;
    }
#pragma unroll
    for (int off = 1; off < 64; off <<= 1) s += __shfl_xor(s, off);
    __shared__ float ls[4];
    if (lane == 0) ls[wvi] = s;
    __syncthreads();
    if (tid == 0) lossp[blockIdx.x] = ls[0] + ls[1] + ls[2] + ls[3];
}

__global__ void loss_final_kernel(const float* __restrict__ lossp, float* __restrict__ out) {
    __shared__ float red[256];
    float s = 0.f;
    for (int i = threadIdx.x; i < N_TOK / 4; i += 256) s += lossp[i];
    red[threadIdx.x] = s;
    __syncthreads();
    for (int st = 128; st > 0; st >>= 1) {
        if (threadIdx.x < st) red[threadIdx.x] += red[threadIdx.x + st];
        __syncthreads();
    }
    if (threadIdx.x == 0) out[(size_t)N_TOK * DIM] = red[0] * (1.25f / 8388608.f);
}

extern "C" void kernel_launch(void* const* d_in, const int* in_sizes, int n_in,
                              void* d_out, int out_size, void* d_ws, size_t ws_size,
                              hipStream_t stream) {
    const float* x = (const float*)d_in[0];   // [16384,512]
    const float* w = (const float*)d_in[1];   // [8192,512]
    float* out = (float*)d_out;               // 16384*512 + 1

    char* W = (char*)d_ws;
    u16*   xint  = (u16*)(W);                        // 32 MiB
    u16*   wint  = (u16*)(W + 33554432);             // 16 MiB
    float* wsq   = (float*)(W + 50331648);           // 32 KiB
    float* wsval = (float*)(W + 50364416);           // 256 KiB
    int*   wsidx = (int*)  (W + 50626560);           // 256 KiB
    float* lossp = (float*)(W + 50888704);           // 16 KiB

    prep_x_kernel<<<N_TOK / 4, 256, 0, stream>>>(x, xint);
    prep_w_kernel<<<N_EMB / 4, 256, 0, stream>>>(w, wint, wsq);
    gemm_argmin_kernel<<<512, 256, 0, stream>>>(xint, wint, wsq, wsval, wsidx);
    gather_loss_kernel<<<N_TOK / 4, 256, 0, stream>>>(w, x, wsval, wsidx, out, lossp);
    loss_final_kernel<<<1, 256, 0, stream>>>(lossp, out);
}

// Round 4
// 444.488 us; speedup vs baseline: 1.1679x; 1.1679x over previous
//
#include <hip/hip_runtime.h>

#define N_TOK 16384
#define N_EMB 8192
#define DIM   512
#define KSPLIT 4
#define KB    (N_EMB / KSPLIT)   // 2048 codes per y-block

typedef __attribute__((ext_vector_type(8))) short bf16x8;
typedef __attribute__((ext_vector_type(16))) float f32x16;
typedef __attribute__((ext_vector_type(4))) unsigned short u16x4;
typedef unsigned short u16;

__device__ __forceinline__ u16 f2bf(float f) {
    unsigned u = __float_as_uint(f);
    u += 0x7fffu + ((u >> 16) & 1u);
    return (u16)(u >> 16);
}
__device__ __forceinline__ float bf2f(u16 h) {
    return __uint_as_float(((unsigned)h) << 16);
}

__device__ __forceinline__ void gload16(const void* g, void* l) {
    __builtin_amdgcn_global_load_lds(
        (const __attribute__((address_space(1))) unsigned int*)g,
        (__attribute__((address_space(3))) unsigned int*)l, 16, 0, 0);
}

// ---------------- prep: split x into bf16 hi/lo (round-1 version) ----------------
__global__ void prep_x_kernel(const float* __restrict__ x,
                              u16* __restrict__ xhi, u16* __restrict__ xlo) {
    int i = (blockIdx.x * 256 + threadIdx.x) * 4;
    float4 v = *(const float4*)(x + i);
    u16x4 h, l;
    h.x = f2bf(v.x); l.x = f2bf(v.x - bf2f(h.x));
    h.y = f2bf(v.y); l.y = f2bf(v.y - bf2f(h.y));
    h.z = f2bf(v.z); l.z = f2bf(v.z - bf2f(h.z));
    h.w = f2bf(v.w); l.w = f2bf(v.w - bf2f(h.w));
    *(u16x4*)(xhi + i) = h;
    *(u16x4*)(xlo + i) = l;
}

// ---------------- prep: split w + wsq (round-1 version) ----------------
__global__ void prep_w_kernel(const float* __restrict__ w,
                              u16* __restrict__ whi, u16* __restrict__ wlo,
                              float* __restrict__ wsq) {
    const int tid = threadIdx.x, lane = tid & 63, wvi = tid >> 6;
    const int row = blockIdx.x * 4 + wvi;
    const float* src = w + (size_t)row * DIM;
    float s = 0.f;
#pragma unroll
    for (int j = 0; j < 2; ++j) {
        int d = j * 256 + lane * 4;
        float4 v = *(const float4*)(src + d);
        u16x4 h, l;
        h.x = f2bf(v.x); l.x = f2bf(v.x - bf2f(h.x));
        h.y = f2bf(v.y); l.y = f2bf(v.y - bf2f(h.y));
        h.z = f2bf(v.z); l.z = f2bf(v.z - bf2f(h.z));
        h.w = f2bf(v.w); l.w = f2bf(v.w - bf2f(h.w));
        *(u16x4*)(whi + (size_t)row * DIM + d) = h;
        *(u16x4*)(wlo + (size_t)row * DIM + d) = l;
        s += v.x * v.x + v.y * v.y + v.z * v.z + v.w * v.w;
    }
#pragma unroll
    for (int off = 1; off < 64; off <<= 1) s += __shfl_xor(s, off);
    if (lane == 0) wsq[row] = s;
}

// ---- main: round-1 structure (drain barriers, [128][64] tiles, g^=(r&7) swizzle),
//      single change: 32x32x16 MFMA fragments.
#define MFMA3(d, ah, al, bh, bl)                                              \
    d = __builtin_amdgcn_mfma_f32_32x32x16_bf16(ah, bh, d, 0, 0, 0);          \
    d = __builtin_amdgcn_mfma_f32_32x32x16_bf16(ah, bl, d, 0, 0, 0);          \
    d = __builtin_amdgcn_mfma_f32_32x32x16_bf16(al, bh, d, 0, 0, 0);

__global__ __launch_bounds__(256, 2)
void gemm_argmin_kernel(const u16* __restrict__ xhi, const u16* __restrict__ xlo,
                        const u16* __restrict__ whi, const u16* __restrict__ wlo,
                        const float* __restrict__ wsq,
                        float* __restrict__ wsval, int* __restrict__ wsidx) {
    // 4 planes of [128 rows][64 dims] bf16 = 64 KiB. Row stride 128 B.
    // 16B granule g of row r stored at position g ^ (r&7)  (round-1 proven).
    __shared__ u16 sm[4][128 * 64];
    const int tid = threadIdx.x;
    const int lane = tid & 63, wv = tid >> 6;
    const int wm = wv >> 1, wn = wv & 1;
    const int RB = blockIdx.x * 128;
    const int CB = blockIdx.y * KB;
    const int l7 = lane & 7, l5 = lane >> 5, l31 = lane & 31;

    float runv[32];
    int   runi[32];
#pragma unroll
    for (int e = 0; e < 32; ++e) { runv[e] = 3.4e38f; runi[e] = 0; }

    const int rA = wm * 64 + l31;   // A rows (mi=0); mi=1 adds +32 rows (+4096 B)
    const int rB = wn * 64 + l31;

    for (int ch = 0; ch < KB / 128; ++ch) {
        const int cb = CB + ch * 128;
        const int c0 = cb + wn * 64 + l31;
        const float wq0 = wsq[c0];
        const float wq1 = wsq[c0 + 32];

        f32x16 acc[2][2];
#pragma unroll
        for (int mi = 0; mi < 2; ++mi)
#pragma unroll
            for (int ni = 0; ni < 2; ++ni)
#pragma unroll
                for (int q = 0; q < 16; ++q) acc[mi][ni][q] = 0.f;

        for (int ds = 0; ds < DIM / 64; ++ds) {
            const int d0 = ds * 64;
            __syncthreads();   // previous step's reads complete
#pragma unroll
            for (int i = 0; i < 4; ++i) {
                int seg = i * 4 + wv;                  // wave-uniform
                int row = seg * 8 + (lane >> 3);       // tile row this lane feeds
                int lc  = (lane & 7) ^ (lane >> 3);    // pre-swizzled granule
                size_t soA = (size_t)(RB + row) * DIM + d0 + lc * 8;
                size_t soB = (size_t)(cb + row) * DIM + d0 + lc * 8;
                gload16(xhi + soA, &sm[0][seg * 512]);
                gload16(xlo + soA, &sm[1][seg * 512]);
                gload16(whi + soB, &sm[2][seg * 512]);
                gload16(wlo + soB, &sm[3][seg * 512]);
            }
            __syncthreads();   // staging drained (compiler emits vmcnt(0))

            const char* base = (const char*)&sm[0][0];
#pragma unroll
            for (int kk = 0; kk < 4; ++kk) {
                const int g = ((kk * 2 + l5) ^ l7) << 4;   // granule pos ^ row&7
                const int offA = rA * 128 + g;
                const int offB = rB * 128 + g;
                bf16x8 ah0 = *(const bf16x8*)(base + offA);
                bf16x8 ah1 = *(const bf16x8*)(base + offA + 4096);
                bf16x8 al0 = *(const bf16x8*)(base + 16384 + offA);
                bf16x8 al1 = *(const bf16x8*)(base + 16384 + offA + 4096);
                bf16x8 bh0 = *(const bf16x8*)(base + 32768 + offB);
                bf16x8 bh1 = *(const bf16x8*)(base + 32768 + offB + 4096);
                bf16x8 bl0 = *(const bf16x8*)(base + 49152 + offB);
                bf16x8 bl1 = *(const bf16x8*)(base + 49152 + offB + 4096);
                __builtin_amdgcn_s_setprio(1);
                MFMA3(acc[0][0], ah0, al0, bh0, bl0);
                MFMA3(acc[0][1], ah0, al0, bh1, bl1);
                MFMA3(acc[1][0], ah1, al1, bh0, bl0);
                MFMA3(acc[1][1], ah1, al1, bh1, bl1);
                __builtin_amdgcn_s_setprio(0);
            }
        }

        // epilogue: score = wsq - 2*S ; streaming argmin (verified 32x32 mapping)
#pragma unroll
        for (int mi = 0; mi < 2; ++mi) {
#pragma unroll
            for (int q = 0; q < 16; ++q) {
                const int e = mi * 16 + q;
                float s0 = wq0 - 2.0f * acc[mi][0][q];
                if (s0 < runv[e]) { runv[e] = s0; runi[e] = c0; }
                float s1 = wq1 - 2.0f * acc[mi][1][q];
                if (s1 < runv[e]) { runv[e] = s1; runi[e] = c0 + 32; }
            }
        }
    }

    // cross-lane argmin reduce over 32 columns per half (verified in round 3)
    __syncthreads();
    float* mv  = (float*)&sm[0][0];                 // [2][128]
    int*   mi_ = (int*)((char*)&sm[0][0] + 1024);   // [2][128]
#pragma unroll
    for (int mi = 0; mi < 2; ++mi) {
#pragma unroll
        for (int q = 0; q < 16; ++q) {
            float v = runv[mi * 16 + q];
            int   ix = runi[mi * 16 + q];
#pragma unroll
            for (int off = 1; off < 32; off <<= 1) {
                float ov = __shfl_xor(v, off);
                int   oi = __shfl_xor(ix, off);
                if (ov < v || (ov == v && oi < ix)) { v = ov; ix = oi; }
            }
            if (l31 == 0) {
                int rl = wm * 64 + mi * 32 + (q & 3) + 8 * (q >> 2) + 4 * l5;
                mv[wn * 128 + rl]  = v;
                mi_[wn * 128 + rl] = ix;
            }
        }
    }
    __syncthreads();
    if (tid < 128) {
        float v0 = mv[tid];       int i0 = mi_[tid];
        float v1 = mv[128 + tid]; int i1 = mi_[128 + tid];
        if (v1 < v0 || (v1 == v0 && i1 < i0)) { v0 = v1; i0 = i1; }
        wsval[(size_t)(RB + tid) * KSPLIT + blockIdx.y] = v0;
        wsidx[(size_t)(RB + tid) * KSPLIT + blockIdx.y] = i0;
    }
}

// ---------------- merge ksplits + gather + loss partials ----------------
__global__ void gather_loss_kernel(const float* __restrict__ w, const float* __restrict__ x,
                                   const float* __restrict__ wsval, const int* __restrict__ wsidx,
                                   float* __restrict__ out, float* __restrict__ lossp) {
    const int tid = threadIdx.x, lane = tid & 63, wvi = tid >> 6;
    const int t = blockIdx.x * 4 + wvi;
    int bi = 0;
    if (lane == 0) {
        float bv = wsval[(size_t)t * KSPLIT];
        bi = wsidx[(size_t)t * KSPLIT];
#pragma unroll
        for (int ks = 1; ks < KSPLIT; ++ks) {
            float v = wsval[(size_t)t * KSPLIT + ks];
            int  ix = wsidx[(size_t)t * KSPLIT + ks];
            if (v < bv || (v == bv && ix < bi)) { bv = v; bi = ix; }
        }
    }
    bi = __shfl(bi, 0);
    const float* wr = w + (size_t)bi * DIM;
    const float* xr = x + (size_t)t * DIM;
    float* orow = out + (size_t)t * DIM;
    float s = 0.f;
#pragma unroll
    for (int j = 0; j < 2; ++j) {
        int d = j * 256 + lane * 4;
        float4 a = *(const float4*)(wr + d);
        float4 b = *(const float4*)(xr + d);
        *(float4*)(orow + d) = a;
        float d0 = a.x - b.x, d1 = a.y - b.y, d2 = a.z - b.z, d3 = a.w - b.w;
        s += d0 * d0 + d1 * d1 + d2 * d2 + d3 * d3;
    }
#pragma unroll
    for (int off = 1; off < 64; off <<= 1) s += __shfl_xor(s, off);
    __shared__ float ls[4];
    if (lane == 0) ls[wvi] = s;
    __syncthreads();
    if (tid == 0) lossp[blockIdx.x] = ls[0] + ls[1] + ls[2] + ls[3];
}

// ---------------- deterministic final loss reduce ----------------
__global__ void loss_final_kernel(const float* __restrict__ lossp, float* __restrict__ out) {
    __shared__ float red[256];
    float s = 0.f;
    for (int i = threadIdx.x; i < N_TOK / 4; i += 256) s += lossp[i];
    red[threadIdx.x] = s;
    __syncthreads();
    for (int st = 128; st > 0; st >>= 1) {
        if (threadIdx.x < st) red[threadIdx.x] += red[threadIdx.x + st];
        __syncthreads();
    }
    // vq_loss = (1 + BETA) * mean((q - x)^2)
    if (threadIdx.x == 0) out[(size_t)N_TOK * DIM] = red[0] * (1.25f / 8388608.f);
}

extern "C" void kernel_launch(void* const* d_in, const int* in_sizes, int n_in,
                              void* d_out, int out_size, void* d_ws, size_t ws_size,
                              hipStream_t stream) {
    const float* x = (const float*)d_in[0];   // [16384,512]
    const float* w = (const float*)d_in[1];   // [8192,512]
    float* out = (float*)d_out;               // 16384*512 + 1

    char* W = (char*)d_ws;
    u16*   xhi   = (u16*)(W);                        // 16 MiB
    u16*   xlo   = (u16*)(W + 16777216);             // 16 MiB
    u16*   whi   = (u16*)(W + 33554432);             // 8 MiB
    u16*   wlo   = (u16*)(W + 41943040);             // 8 MiB
    float* wsq   = (float*)(W + 50331648);           // 32 KiB
    float* wsval = (float*)(W + 50364416);           // 256 KiB
    int*   wsidx = (int*)  (W + 50626560);           // 256 KiB
    float* lossp = (float*)(W + 50888704);           // 16 KiB

    prep_x_kernel<<<N_TOK * DIM / 1024, 256, 0, stream>>>(x, xhi, xlo);
    prep_w_kernel<<<N_EMB / 4, 256, 0, stream>>>(w, whi, wlo, wsq);
    dim3 g(N_TOK / 128, KSPLIT);
    gemm_argmin_kernel<<<g, 256, 0, stream>>>(xhi, xlo, whi, wlo, wsq, wsval, wsidx);
    gather_loss_kernel<<<N_TOK / 4, 256, 0, stream>>>(w, x, wsval, wsidx, out, lossp);
    loss_final_kernel<<<1, 256, 0, stream>>>(lossp, out);
}

// Round 5
// 379.847 us; speedup vs baseline: 1.3667x; 1.1702x over previous
//
#include <hip/hip_runtime.h>

#define N_TOK 16384
#define N_EMB 8192
#define DIM   512
#define KSPLIT 4
#define KB    (N_EMB / KSPLIT)   // 2048 codes per y-block

typedef __attribute__((ext_vector_type(8))) short bf16x8;
typedef __attribute__((ext_vector_type(4))) float f32x4;
typedef unsigned short u16;

__device__ __forceinline__ u16 f2bf(float f) {
    unsigned u = __float_as_uint(f);
    u += 0x7fffu + ((u >> 16) & 1u);
    return (u16)(u >> 16);
}
__device__ __forceinline__ float bf2f(u16 h) {
    return __uint_as_float(((unsigned)h) << 16);
}

__device__ __forceinline__ void gload16(const void* g, void* l) {
    __builtin_amdgcn_global_load_lds(
        (const __attribute__((address_space(1))) unsigned int*)g,
        (__attribute__((address_space(3))) unsigned int*)l, 16, 0, 0);
}

// ---- prep: interleaved split layout: [row][16 kblocks][32 hi | 32 lo] bf16 (128 B lines)
//      (verified bit-exact in round 3)
__global__ void prep_x_kernel(const float* __restrict__ x, u16* __restrict__ xint) {
    const int tid = threadIdx.x, lane = tid & 63, wvi = tid >> 6;
    const int row = blockIdx.x * 4 + wvi;
    const float* src = x + (size_t)row * DIM + lane * 8;
    float4 v0 = *(const float4*)src;
    float4 v1 = *(const float4*)(src + 4);
    float vv[8] = {v0.x, v0.y, v0.z, v0.w, v1.x, v1.y, v1.z, v1.w};
    bf16x8 hv, lv;
#pragma unroll
    for (int i = 0; i < 8; ++i) {
        u16 h = f2bf(vv[i]);
        hv[i] = (short)h;
        lv[i] = (short)f2bf(vv[i] - bf2f(h));
    }
    u16* dst = xint + (size_t)row * 1024 + (lane >> 2) * 64 + (lane & 3) * 8;
    *(bf16x8*)dst = hv;
    *(bf16x8*)(dst + 32) = lv;
}

__global__ void prep_w_kernel(const float* __restrict__ w, u16* __restrict__ wint,
                              float* __restrict__ wsq) {
    const int tid = threadIdx.x, lane = tid & 63, wvi = tid >> 6;
    const int row = blockIdx.x * 4 + wvi;
    const float* src = w + (size_t)row * DIM + lane * 8;
    float4 v0 = *(const float4*)src;
    float4 v1 = *(const float4*)(src + 4);
    float vv[8] = {v0.x, v0.y, v0.z, v0.w, v1.x, v1.y, v1.z, v1.w};
    bf16x8 hv, lv;
    float s = 0.f;
#pragma unroll
    for (int i = 0; i < 8; ++i) {
        u16 h = f2bf(vv[i]);
        hv[i] = (short)h;
        lv[i] = (short)f2bf(vv[i] - bf2f(h));
        s += vv[i] * vv[i];
    }
    u16* dst = wint + (size_t)row * 1024 + (lane >> 2) * 64 + (lane & 3) * 8;
    *(bf16x8*)dst = hv;
    *(bf16x8*)(dst + 32) = lv;
#pragma unroll
    for (int off = 1; off < 64; off <<= 1) s += __shfl_xor(s, off);
    if (lane == 0) wsq[row] = s;
}

// ---- main: 3-pass split-bf16 GEMM, 16x16x32 frags (proven zero-conflict pattern),
//      BK=32 double-buffer with counted vmcnt (T3/T4-minimal), streaming argmin.
// LDS: [buf 2][plane A/B][128 rows][128 B: 8 granules of 16 B].
// Granule g of row r stored at position g ^ (r & 7)  (round-1 proven shape).
#define MFMA3(d, ah, al, bh, bl)                                              \
    d = __builtin_amdgcn_mfma_f32_16x16x32_bf16(ah, bh, d, 0, 0, 0);          \
    d = __builtin_amdgcn_mfma_f32_16x16x32_bf16(ah, bl, d, 0, 0, 0);          \
    d = __builtin_amdgcn_mfma_f32_16x16x32_bf16(al, bh, d, 0, 0, 0);

__global__ __launch_bounds__(256, 2)
void gemm_argmin_kernel(const u16* __restrict__ xint, const u16* __restrict__ wint,
                        const float* __restrict__ wsq,
                        float* __restrict__ wsval, int* __restrict__ wsidx) {
    __shared__ u16 sm[2][2][128 * 64];   // 2 buf x (A,B) x 16 KiB = 64 KiB
    const int tid = threadIdx.x;
    const int lane = tid & 63, wv = tid >> 6;
    const int wm = wv >> 1, wn = wv & 1;
    const int RB = blockIdx.x * 128;
    const int CB = blockIdx.y * KB;
    const int l15 = lane & 15, l4 = lane >> 4;

    float runv[16];
    int   runi[16];
#pragma unroll
    for (int e = 0; e < 16; ++e) { runv[e] = 3.4e38f; runi[e] = 0; }

    // staging pieces: lane feeds row seg*8 + (lane>>3), granule position lane&7,
    // which must hold source granule (lane&7) ^ (r&7) = (lane&7) ^ ((lane>>3)&7)
    const int sg = (lane & 7) ^ ((lane >> 3) & 7);
    const int srow = lane >> 3;

    auto stage = [&](int t) {
        const int buf = t & 1;
        const int kb = t & 15;
        const int cb = CB + (t >> 4) * 128;
        u16* dstA = &sm[buf][0][0];
        u16* dstB = &sm[buf][1][0];
#pragma unroll
        for (int j = 0; j < 4; ++j) {
            int seg = wv * 4 + j;                  // wave-uniform 0..15
            int r = seg * 8 + srow;
            gload16(xint + (size_t)(RB + r) * 1024 + kb * 64 + sg * 8, dstA + seg * 512);
            gload16(wint + (size_t)(cb + r) * 1024 + kb * 64 + sg * 8, dstB + seg * 512);
        }
    };

    stage(0);
    stage(1);

    f32x4 acc[4][4];
    float wq[4];

    for (int t = 0; t < 256; ++t) {
        // tile t landed when <=8 issues (tile t+1) remain outstanding
        if (t < 255) asm volatile("s_waitcnt vmcnt(8)" ::: "memory");
        else         asm volatile("s_waitcnt vmcnt(0)" ::: "memory");
        __builtin_amdgcn_s_barrier();

        if ((t & 15) == 0) {
            const int c0 = CB + (t >> 4) * 128;
#pragma unroll
            for (int ni = 0; ni < 4; ++ni)
                wq[ni] = wsq[c0 + wn * 64 + ni * 16 + l15];
#pragma unroll
            for (int mi = 0; mi < 4; ++mi)
#pragma unroll
                for (int ni = 0; ni < 4; ++ni)
                    acc[mi][ni] = (f32x4){0.f, 0.f, 0.f, 0.f};
        }

        const char* baseA = (const char*)&sm[t & 1][0][0];
        const char* baseB = (const char*)&sm[t & 1][1][0];
        bf16x8 ah[4], al[4], bh[4], bl[4];
#pragma unroll
        for (int mi = 0; mi < 4; ++mi) {
            int r = wm * 64 + mi * 16 + l15;
            int off = r * 128 + ((l4 ^ (r & 7)) << 4);   // hi granule l4 (0..3)
            ah[mi] = *(const bf16x8*)(baseA + off);
            al[mi] = *(const bf16x8*)(baseA + (off ^ 64)); // lo granule = hi ^ 4
        }
#pragma unroll
        for (int ni = 0; ni < 4; ++ni) {
            int r = wn * 64 + ni * 16 + l15;
            int off = r * 128 + ((l4 ^ (r & 7)) << 4);
            bh[ni] = *(const bf16x8*)(baseB + off);
            bl[ni] = *(const bf16x8*)(baseB + (off ^ 64));
        }
        __builtin_amdgcn_s_setprio(1);
#pragma unroll
        for (int mi = 0; mi < 4; ++mi)
#pragma unroll
            for (int ni = 0; ni < 4; ++ni) {
                MFMA3(acc[mi][ni], ah[mi], al[mi], bh[ni], bl[ni]);
            }
        __builtin_amdgcn_s_setprio(0);

        // all reads of buf[t&1] retired before anyone overwrites it
        asm volatile("s_waitcnt lgkmcnt(0)" ::: "memory");
        __builtin_amdgcn_sched_barrier(0);
        __builtin_amdgcn_s_barrier();
        if (t < 254) stage(t + 2);

        if ((t & 15) == 15) {
            // epilogue: score = wsq - 2*S ; streaming argmin (cols ascending)
            const int cb = CB + (t >> 4) * 128;
#pragma unroll
            for (int mi = 0; mi < 4; ++mi)
#pragma unroll
                for (int ni = 0; ni < 4; ++ni) {
                    int idx = cb + wn * 64 + ni * 16 + l15;
#pragma unroll
                    for (int r = 0; r < 4; ++r) {
                        float sc = wq[ni] - 2.0f * acc[mi][ni][r];
                        int e = mi * 4 + r;
                        if (sc < runv[e]) { runv[e] = sc; runi[e] = idx; }
                    }
                }
        }
    }

    // cross-lane reduce (R1-verified): lanes of a 16-group share rows, own cols
    __syncthreads();
    float* mv  = (float*)&sm[0][0][0];                 // [2][128]
    int*   mi_ = (int*)((char*)&sm[0][0][0] + 1024);   // [2][128]
#pragma unroll
    for (int e = 0; e < 16; ++e) {
        float v = runv[e];
        int   ix = runi[e];
#pragma unroll
        for (int off = 1; off < 16; off <<= 1) {
            float ov = __shfl_xor(v, off);
            int   oi = __shfl_xor(ix, off);
            if (ov < v || (ov == v && oi < ix)) { v = ov; ix = oi; }
        }
        if (l15 == 0) {
            int rl = wm * 64 + (e >> 2) * 16 + l4 * 4 + (e & 3);
            mv[wn * 128 + rl]  = v;
            mi_[wn * 128 + rl] = ix;
        }
    }
    __syncthreads();
    if (tid < 128) {
        float v0 = mv[tid];       int i0 = mi_[tid];
        float v1 = mv[128 + tid]; int i1 = mi_[128 + tid];
        if (v1 < v0 || (v1 == v0 && i1 < i0)) { v0 = v1; i0 = i1; }
        wsval[(size_t)(RB + tid) * KSPLIT + blockIdx.y] = v0;
        wsidx[(size_t)(RB + tid) * KSPLIT + blockIdx.y] = i0;
    }
}

// ---------------- merge ksplits + gather + loss partials ----------------
__global__ void gather_loss_kernel(const float* __restrict__ w, const float* __restrict__ x,
                                   const float* __restrict__ wsval, const int* __restrict__ wsidx,
                                   float* __restrict__ out, float* __restrict__ lossp) {
    const int tid = threadIdx.x, lane = tid & 63, wvi = tid >> 6;
    const int t = blockIdx.x * 4 + wvi;
    int bi = 0;
    if (lane == 0) {
        float bv = wsval[(size_t)t * KSPLIT];
        bi = wsidx[(size_t)t * KSPLIT];
#pragma unroll
        for (int ks = 1; ks < KSPLIT; ++ks) {
            float v = wsval[(size_t)t * KSPLIT + ks];
            int  ix = wsidx[(size_t)t * KSPLIT + ks];
            if (v < bv || (v == bv && ix < bi)) { bv = v; bi = ix; }
        }
    }
    bi = __shfl(bi, 0);
    const float* wr = w + (size_t)bi * DIM;
    const float* xr = x + (size_t)t * DIM;
    float* orow = out + (size_t)t * DIM;
    float s = 0.f;
#pragma unroll
    for (int j = 0; j < 2; ++j) {
        int d = j * 256 + lane * 4;
        float4 a = *(const float4*)(wr + d);
        float4 b = *(const float4*)(xr + d);
        *(float4*)(orow + d) = a;
        float d0 = a.x - b.x, d1 = a.y - b.y, d2 = a.z - b.z, d3 = a.w - b.w;
        s += d0 * d0 + d1 * d1 + d2 * d2 + d3 * d3;
    }
#pragma unroll
    for (int off = 1; off < 64; off <<= 1) s += __shfl_xor(s, off);
    __shared__ float ls[4];
    if (lane == 0) ls[wvi] = s;
    __syncthreads();
    if (tid == 0) lossp[blockIdx.x] = ls[0] + ls[1] + ls[2] + ls[3];
}

// ---------------- deterministic final loss reduce ----------------
__global__ void loss_final_kernel(const float* __restrict__ lossp, float* __restrict__ out) {
    __shared__ float red[256];
    float s = 0.f;
    for (int i = threadIdx.x; i < N_TOK / 4; i += 256) s += lossp[i];
    red[threadIdx.x] = s;
    __syncthreads();
    for (int st = 128; st > 0; st >>= 1) {
        if (threadIdx.x < st) red[threadIdx.x] += red[threadIdx.x + st];
        __syncthreads();
    }
    // vq_loss = (1 + BETA) * mean((q - x)^2)
    if (threadIdx.x == 0) out[(size_t)N_TOK * DIM] = red[0] * (1.25f / 8388608.f);
}

extern "C" void kernel_launch(void* const* d_in, const int* in_sizes, int n_in,
                              void* d_out, int out_size, void* d_ws, size_t ws_size,
                              hipStream_t stream) {
    const float* x = (const float*)d_in[0];   // [16384,512]
    const float* w = (const float*)d_in[1];   // [8192,512]
    float* out = (float*)d_out;               // 16384*512 + 1

    char* W = (char*)d_ws;
    u16*   xint  = (u16*)(W);                        // 32 MiB
    u16*   wint  = (u16*)(W + 33554432);             // 16 MiB
    float* wsq   = (float*)(W + 50331648);           // 32 KiB
    float* wsval = (float*)(W + 50364416);           // 256 KiB
    int*   wsidx = (int*)  (W + 50626560);           // 256 KiB
    float* lossp = (float*)(W + 50888704);           // 16 KiB

    prep_x_kernel<<<N_TOK / 4, 256, 0, stream>>>(x, xint);
    prep_w_kernel<<<N_EMB / 4, 256, 0, stream>>>(w, wint, wsq);
    dim3 g(N_TOK / 128, KSPLIT);
    gemm_argmin_kernel<<<g, 256, 0, stream>>>(xint, wint, wsq, wsval, wsidx);
    gather_loss_kernel<<<N_TOK / 4, 256, 0, stream>>>(w, x, wsval, wsidx, out, lossp);
    loss_final_kernel<<<1, 256, 0, stream>>>(lossp, out);
}